// Round 9
// baseline (326.482 us; speedup 1.0000x reference)
//
#include <hip/hip_runtime.h>

// ---------- types ----------
typedef __attribute__((ext_vector_type(4))) float  f32x4;
typedef __attribute__((ext_vector_type(8))) short  s16x8;   // 8 bf16 (4 VGPRs)
typedef __attribute__((ext_vector_type(8))) unsigned short u16x8;
typedef __attribute__((ext_vector_type(4))) unsigned short u16x4;

static __device__ __forceinline__ unsigned short f2bf(float f) {
    unsigned int u = __builtin_bit_cast(unsigned int, f);
    u += 0x7fffu + ((u >> 16) & 1u);      // round-to-nearest-even
    return (unsigned short)(u >> 16);
}

static __device__ __forceinline__ unsigned int cvt_pk_bf16(float lo, float hi) {
    unsigned int r;
    asm("v_cvt_pk_bf16_f32 %0, %1, %2" : "=v"(r) : "v"(lo), "v"(hi));
    return r;
}

static __device__ __forceinline__ void gload16(const void* g, void* l) {
    __builtin_amdgcn_global_load_lds(
        (const __attribute__((address_space(1))) void*)g,
        (__attribute__((address_space(3))) void*)l, 16, 0, 0);
}

// =====================================================================
// fp32 -> bf16 convert pass: q,k,v + 4 weights. 2048 elems/block.
// =====================================================================
__global__ __launch_bounds__(256)
void conv_kernel(const float* __restrict__ q, const float* __restrict__ k,
                 const float* __restrict__ v,
                 const float* __restrict__ wq, const float* __restrict__ wk,
                 const float* __restrict__ wv, const float* __restrict__ wo,
                 unsigned short* __restrict__ qb, unsigned short* __restrict__ kb,
                 unsigned short* __restrict__ vb, unsigned short* __restrict__ wb)
{
    const int bid = blockIdx.x;
    const float* src; unsigned short* dst; int inner;
    if      (bid < 4096)  { src = q;  dst = qb; inner = bid; }
    else if (bid < 8192)  { src = k;  dst = kb; inner = bid - 4096; }
    else if (bid < 12288) { src = v;  dst = vb; inner = bid - 8192; }
    else {
        const int wseg = (bid - 12288) >> 9;
        src = wseg == 0 ? wq : wseg == 1 ? wk : wseg == 2 ? wv : wo;
        dst = wb + (size_t)wseg * 1048576;
        inner = (bid - 12288) & 511;
    }
    const size_t e0 = (size_t)inner * 2048 + threadIdx.x * 8;
    f32x4 a = *(const f32x4*)(src + e0);
    f32x4 b = *(const f32x4*)(src + e0 + 4);
    u16x8 o;
    #pragma unroll
    for (int i = 0; i < 4; ++i) { o[i] = f2bf(a[i]); o[i + 4] = f2bf(b[i]); }
    *(u16x8*)(dst + e0) = o;
}

// =====================================================================
// LDS-FREE bf16 NT GEMM: fragments loaded L2 -> registers directly.
// All operands are L2-resident (A panels shared by same-XCD bx-neighbors
// via swizzle; B = 2 MB weights). No LDS, no barriers; 1-deep register
// pipeline (static frag names); 3 blocks/CU for cross-block overlap.
// 128x128 tile, 4 waves (2x2, per-wave 64x64).
// EPI 0: fused QKV. grid 1536 (3 seg x 64 by x 8 bx), XCD-swizzled.
//        seg0 -> Qh [B,H,L,64] * 0.125 ; seg1 -> Kh ; seg2 -> Vt [B,H,64,L]
// EPI 1: out proj. grid 512. Of fp32 [8192,1024].
// =====================================================================
template<int EPI>
__global__ __launch_bounds__(256, 3)
void gemmR(const unsigned short* __restrict__ A0,
           const unsigned short* __restrict__ A1,
           const unsigned short* __restrict__ A2,
           const unsigned short* __restrict__ Bw,
           unsigned short* __restrict__ O0, unsigned short* __restrict__ O1,
           unsigned short* __restrict__ O2, float* __restrict__ Of)
{
    const int tid  = threadIdx.x;
    const int lane = tid & 63;
    const int wave = tid >> 6;
    const int wr   = wave >> 1, wc = wave & 1;    // 2x2 waves, 64x64 each
    const int g    = lane >> 4, l16 = lane & 15;

    const int nblk = (EPI == 0) ? 1536 : 512;
    const int cpx  = nblk >> 3;
    const int wg   = (blockIdx.x & 7) * cpx + (blockIdx.x >> 3);  // bijective XCD swizzle
    const int bx   = wg & 7;
    const int byt  = wg >> 3;
    const int seg  = (EPI == 0) ? (byt >> 6) : 0;
    const int byl  = (EPI == 0) ? (byt & 63) : byt;

    const unsigned short* Ap = (EPI == 0) ? (seg == 0 ? A0 : seg == 1 ? A1 : A2) : A0;
    // per-lane fragment bases: row = tile_row + l16, col-elems = g*8
    const unsigned short* Abase = Ap + (size_t)(byl * 128 + wr * 64 + l16) * 1024 + g * 8;
    const unsigned short* Bbase = Bw + (size_t)seg * 1048576
                                + (size_t)(bx * 128 + wc * 64 + l16) * 1024 + g * 8;

    f32x4 acc[4][4] = {};
    s16x8 aA[4], bA[4], aB[4], bB[4];

#define LOADF(AF, BF, KT)                                                          \
    {                                                                              \
        _Pragma("unroll")                                                          \
        for (int mi = 0; mi < 4; ++mi)                                             \
            AF[mi] = __builtin_bit_cast(s16x8,                                     \
                *(const u16x8*)(Abase + (size_t)mi * 16384 + (KT) * 32));          \
        _Pragma("unroll")                                                          \
        for (int ni = 0; ni < 4; ++ni)                                             \
            BF[ni] = __builtin_bit_cast(s16x8,                                     \
                *(const u16x8*)(Bbase + (size_t)ni * 16384 + (KT) * 32));          \
    }

#define MFMAR(AF, BF)                                                              \
    {                                                                              \
        __builtin_amdgcn_s_setprio(1);                                             \
        _Pragma("unroll")                                                          \
        for (int mi = 0; mi < 4; ++mi) {                                           \
            _Pragma("unroll")                                                      \
            for (int ni = 0; ni < 4; ++ni)                                         \
                acc[mi][ni] = __builtin_amdgcn_mfma_f32_16x16x32_bf16(             \
                    AF[mi], BF[ni], acc[mi][ni], 0, 0, 0);                         \
        }                                                                          \
        __builtin_amdgcn_s_setprio(0);                                             \
    }

    LOADF(aA, bA, 0)
    for (int kt = 0; kt < 32; kt += 2) {       // K-chunks of 32 (one MFMA-K each)
        LOADF(aB, bB, kt + 1)
        MFMAR(aA, bA)
        if (kt + 2 < 32) LOADF(aA, bA, kt + 2)
        MFMAR(aB, bB)
    }
#undef LOADF
#undef MFMAR

    // ---- epilogue ----
    #pragma unroll
    for (int mi = 0; mi < 4; ++mi) {
        #pragma unroll
        for (int ni = 0; ni < 4; ++ni) {
            const int gr0 = byl * 128 + wr * 64 + mi * 16 + g * 4;      // M base
            const int gc  = bx * 128 + wc * 64 + ni * 16 + l16;         // N
            if (EPI == 0 && seg == 2) {
                // Vt [B,H,64,L]: pack 4 consecutive ll into one 8B store
                const int b = gr0 >> 11, ll = gr0 & 2047;
                const int h = gc >> 6,  dh = gc & 63;
                u16x4 pk;
                #pragma unroll
                for (int rr = 0; rr < 4; ++rr) pk[rr] = f2bf(acc[mi][ni][rr]);
                *(u16x4*)(O2 + (size_t)((b * 16 + h) * 64 + dh) * 2048 + ll) = pk;
            } else {
                #pragma unroll
                for (int rr = 0; rr < 4; ++rr) {
                    const int gr = gr0 + rr;
                    float v = acc[mi][ni][rr];
                    if (EPI == 0) {
                        const int b = gr >> 11, ll = gr & 2047;
                        const int h = gc >> 6,  dh = gc & 63;
                        if (seg == 0) {
                            v *= 0.125f;
                            O0[(size_t)((b * 16 + h) * 2048 + ll) * 64 + dh] = f2bf(v);
                        } else {
                            O1[(size_t)((b * 16 + h) * 2048 + ll) * 64 + dh] = f2bf(v);
                        }
                    } else {
                        Of[(size_t)gr * 1024 + gc] = v;
                    }
                }
            }
        }
    }
}

// =====================================================================
// Fallback GEMM (fp32 inputs converted in-loop) — only used if ws too small.
// =====================================================================
template<int AM, int BM, int EPI>
__global__ __launch_bounds__(256)
void gemm_k(const void* __restrict__ A0, const void* __restrict__ A1,
            const void* __restrict__ A2,
            const void* __restrict__ B0, const void* __restrict__ B1,
            const void* __restrict__ B2,
            unsigned short* __restrict__ O0, unsigned short* __restrict__ O1,
            unsigned short* __restrict__ O2, float* __restrict__ Of)
{
    __shared__ unsigned short Asw[128 * 64];
    __shared__ unsigned short Bsw[128 * 64];

    const int tid  = threadIdx.x;
    const int lane = tid & 63;
    const int wave = tid >> 6;
    const int wr   = wave >> 1, wc = wave & 1;
    const int g    = lane >> 4, l16 = lane & 15;

    const int nper = (EPI == 0) ? 192 : 64;
    const int wg   = (blockIdx.x & 7) * nper + (blockIdx.x >> 3);
    const int bx   = wg & 7;
    const int by   = wg >> 3;
    const int seg  = (EPI == 0) ? (by >> 6) : 0;
    const int byl  = (EPI == 0) ? (by & 63) : by;

    const void* Ap = seg == 0 ? A0 : seg == 1 ? A1 : A2;
    const void* Bp = seg == 0 ? B0 : seg == 1 ? B1 : B2;

    f32x4 acc[4][4] = {};

    for (int kt = 0; kt < 16; ++kt) {
        __syncthreads();
        if (AM == 0) {
            #pragma unroll
            for (int j = 0; j < 4; ++j) {
                const int idx = j * 256 + tid;
                const int r   = idx >> 3;
                const int cl  = (tid & 7) ^ (r & 7);
                gload16((const unsigned short*)Ap + (size_t)(byl * 128 + r) * 1024 + kt * 64 + cl * 8,
                        (char*)Asw + j * 4096 + wave * 1024);
            }
        } else {
            #pragma unroll
            for (int j = 0; j < 4; ++j) {
                const int idx = j * 256 + tid;
                const int r = idx >> 3, c = tid & 7;
                const float* src = (const float*)Ap + (size_t)(byl * 128 + r) * 1024 + kt * 64 + c * 8;
                f32x4 a = *(const f32x4*)src;
                f32x4 b = *(const f32x4*)(src + 4);
                u16x8 w;
                #pragma unroll
                for (int i = 0; i < 4; ++i) { w[i] = f2bf(a[i]); w[i + 4] = f2bf(b[i]); }
                *(u16x8*)((char*)Asw + ((r * 128 + c * 16) ^ ((r & 7) << 4))) = w;
            }
        }
        if (BM == 0) {
            #pragma unroll
            for (int j = 0; j < 4; ++j) {
                const int idx = j * 256 + tid;
                const int r   = idx >> 3;
                const int cl  = (tid & 7) ^ (r & 7);
                gload16((const unsigned short*)Bp + (size_t)(bx * 128 + r) * 1024 + kt * 64 + cl * 8,
                        (char*)Bsw + j * 4096 + wave * 1024);
            }
        } else {
            #pragma unroll
            for (int j = 0; j < 4; ++j) {
                const int idx = j * 256 + tid;
                const int r = idx >> 3, c = tid & 7;
                const float* src = (const float*)Bp + (size_t)(bx * 128 + r) * 1024 + kt * 64 + c * 8;
                f32x4 a = *(const f32x4*)src;
                f32x4 b = *(const f32x4*)(src + 4);
                u16x8 w;
                #pragma unroll
                for (int i = 0; i < 4; ++i) { w[i] = f2bf(a[i]); w[i + 4] = f2bf(b[i]); }
                *(u16x8*)((char*)Bsw + ((r * 128 + c * 16) ^ ((r & 7) << 4))) = w;
            }
        }
        __syncthreads();

        #pragma unroll
        for (int ks = 0; ks < 2; ++ks) {
            s16x8 af[4], bf[4];
            #pragma unroll
            for (int mi = 0; mi < 4; ++mi) {
                const int row = wr * 64 + mi * 16 + l16;
                const int off = (row * 128 + g * 16 + ks * 64) ^ ((row & 7) << 4);
                af[mi] = __builtin_bit_cast(s16x8, *(const u16x8*)((const char*)Asw + off));
            }
            #pragma unroll
            for (int ni = 0; ni < 4; ++ni) {
                const int row = wc * 64 + ni * 16 + l16;
                const int off = (row * 128 + g * 16 + ks * 64) ^ ((row & 7) << 4);
                bf[ni] = __builtin_bit_cast(s16x8, *(const u16x8*)((const char*)Bsw + off));
            }
            #pragma unroll
            for (int mi = 0; mi < 4; ++mi)
                #pragma unroll
                for (int ni = 0; ni < 4; ++ni)
                    acc[mi][ni] = __builtin_amdgcn_mfma_f32_16x16x32_bf16(
                        af[mi], bf[ni], acc[mi][ni], 0, 0, 0);
        }
    }

    #pragma unroll
    for (int mi = 0; mi < 4; ++mi) {
        #pragma unroll
        for (int ni = 0; ni < 4; ++ni) {
            #pragma unroll
            for (int rr = 0; rr < 4; ++rr) {
                const int gr = byl * 128 + wr * 64 + mi * 16 + g * 4 + rr;
                const int gc = bx * 128 + wc * 64 + ni * 16 + l16;
                float v = acc[mi][ni][rr];
                if (EPI == 0) {
                    const int b = gr >> 11, ll = gr & 2047, h = gc >> 6, dh = gc & 63;
                    if (seg == 0) {
                        v *= 0.125f;
                        O0[(size_t)((b * 16 + h) * 2048 + ll) * 64 + dh] = f2bf(v);
                    } else if (seg == 1) {
                        O1[(size_t)((b * 16 + h) * 2048 + ll) * 64 + dh] = f2bf(v);
                    } else {
                        O2[(size_t)((b * 16 + h) * 64 + dh) * 2048 + ll] = f2bf(v);
                    }
                } else {
                    Of[(size_t)gr * 1024 + gc] = v;
                }
            }
        }
    }
}

// =====================================================================
// Flash-style causal attention (unchanged from R5/R6).
// =====================================================================
__global__ __launch_bounds__(512)
void attn_kernel(const unsigned short* __restrict__ Qh,
                 const unsigned short* __restrict__ Kh,
                 const unsigned short* __restrict__ Vt,
                 unsigned short* __restrict__ Ctx)
{
    __shared__ unsigned short Ksw[2][64 * 64];
    __shared__ unsigned short Vsw[2][64 * 64];
    __shared__ unsigned short Psw[8][16 * 64];

    const int tid  = threadIdx.x;
    const int lane = tid & 63;
    const int wave = tid >> 6;
    const int g    = lane >> 4, l16 = lane & 15;
    const int qb   = 15 - (int)(blockIdx.x >> 6);
    const int bh   = blockIdx.x & 63;
    const int b    = bh >> 4, h = bh & 15;
    const int qrow0 = qb * 128 + wave * 16;
    const int ntile = 2 * qb + 2;

    const int sr = tid >> 3, sc = tid & 7;
    const int soff = (sr * 128 + sc * 16) ^ ((sr & 7) << 4);
    const unsigned short* kbase = Kh + ((size_t)bh * 2048 + sr) * 64 + sc * 8;
    const unsigned short* vbase = Vt + ((size_t)bh * 64 + sr) * 2048 + sc * 8;

    s16x8 qf[2];
    {
        const unsigned short* qp = Qh + ((size_t)bh * 2048 + qrow0 + l16) * 64 + g * 8;
        qf[0] = __builtin_bit_cast(s16x8, *(const u16x8*)qp);
        qf[1] = __builtin_bit_cast(s16x8, *(const u16x8*)(qp + 32));
    }

    f32x4 o[4] = {};
    float m = -3.0e38f, l = 0.f;   // per-lane row state: q = l16

    *(u16x8*)((char*)Ksw[0] + soff) = *(const u16x8*)kbase;
    *(u16x8*)((char*)Vsw[0] + soff) = *(const u16x8*)vbase;
    __syncthreads();

    int cur = 0;
    for (int t = 0; t < ntile; ++t) {
        const int kv0 = t * 64;

        u16x8 kn, vn;
        const bool hn = (t + 1 < ntile);
        if (hn) {
            kn = *(const u16x8*)(kbase + (size_t)(kv0 + 64) * 64);
            vn = *(const u16x8*)(vbase + (kv0 + 64));
        }

        if (kv0 <= qrow0 + 15) {
            const char* Kb = (const char*)Ksw[cur];
            const char* Vb = (const char*)Vsw[cur];

            f32x4 st[4] = {};
            __builtin_amdgcn_s_setprio(1);
            #pragma unroll
            for (int nt = 0; nt < 4; ++nt) {
                #pragma unroll
                for (int ks = 0; ks < 2; ++ks) {
                    const int row = nt * 16 + l16;
                    const int off = (row * 128 + g * 16 + ks * 64) ^ ((row & 7) << 4);
                    s16x8 kf = __builtin_bit_cast(s16x8, *(const u16x8*)(Kb + off));
                    st[nt] = __builtin_amdgcn_mfma_f32_16x16x32_bf16(kf, qf[ks], st[nt], 0, 0, 0);
                }
            }
            __builtin_amdgcn_s_setprio(0);

            if (kv0 + 63 > qrow0) {
                const int q_g = qrow0 + l16;
                #pragma unroll
                for (int nt = 0; nt < 4; ++nt)
                    #pragma unroll
                    for (int rr = 0; rr < 4; ++rr) {
                        const int kv_g = kv0 + nt * 16 + g * 4 + rr;
                        if (kv_g > q_g) st[nt][rr] = -3.0e38f;
                    }
            }

            float pmax = fmaxf(
                fmaxf(fmaxf(fmaxf(st[0][0], st[0][1]), fmaxf(st[0][2], st[0][3])),
                      fmaxf(fmaxf(st[1][0], st[1][1]), fmaxf(st[1][2], st[1][3]))),
                fmaxf(fmaxf(fmaxf(st[2][0], st[2][1]), fmaxf(st[2][2], st[2][3])),
                      fmaxf(fmaxf(st[3][0], st[3][1]), fmaxf(st[3][2], st[3][3]))));
            pmax = fmaxf(pmax, __shfl_xor(pmax, 16));
            pmax = fmaxf(pmax, __shfl_xor(pmax, 32));

            if (__all(pmax <= m + 8.0f)) {
                float r0 = 0.f;
                #pragma unroll
                for (int nt = 0; nt < 4; ++nt)
                    #pragma unroll
                    for (int rr = 0; rr < 4; ++rr) {
                        const float p = __expf(st[nt][rr] - m);
                        st[nt][rr] = p;
                        r0 += p;
                    }
                r0 += __shfl_xor(r0, 16);
                r0 += __shfl_xor(r0, 32);
                l += r0;
            } else {
                const float mn = fmaxf(m, pmax);
                const float scf = __expf(m - mn);
                m = mn;
                float r0 = 0.f;
                #pragma unroll
                for (int nt = 0; nt < 4; ++nt)
                    #pragma unroll
                    for (int rr = 0; rr < 4; ++rr) {
                        const float p = __expf(st[nt][rr] - mn);
                        st[nt][rr] = p;
                        r0 += p;
                    }
                r0 += __shfl_xor(r0, 16);
                r0 += __shfl_xor(r0, 32);
                l = l * scf + r0;
                float sc4[4];
                #pragma unroll
                for (int rr = 0; rr < 4; ++rr) sc4[rr] = __shfl(scf, g * 4 + rr);
                #pragma unroll
                for (int nt = 0; nt < 4; ++nt)
                    #pragma unroll
                    for (int rr = 0; rr < 4; ++rr)
                        o[nt][rr] *= sc4[rr];
            }

            unsigned short* Pw = Psw[wave];
            #pragma unroll
            for (int nt = 0; nt < 4; ++nt) {
                const unsigned int w0 = cvt_pk_bf16(st[nt][0], st[nt][1]);
                const unsigned int w1 = cvt_pk_bf16(st[nt][2], st[nt][3]);
                const int off = (l16 * 128 + nt * 32 + g * 8) ^ ((l16 & 7) << 4);
                const unsigned long long dw = ((unsigned long long)w1 << 32) | w0;
                *(unsigned long long*)((char*)Pw + off) = dw;
            }

            __builtin_amdgcn_s_setprio(1);
            #pragma unroll
            for (int ks = 0; ks < 2; ++ks) {
                const int offp = (l16 * 128 + g * 16 + ks * 64) ^ ((l16 & 7) << 4);
                s16x8 pf = __builtin_bit_cast(s16x8, *(const u16x8*)((const char*)Pw + offp));
                #pragma unroll
                for (int nt = 0; nt < 4; ++nt) {
                    const int row = nt * 16 + l16;
                    const int off = (row * 128 + g * 16 + ks * 64) ^ ((row & 7) << 4);
                    s16x8 vf = __builtin_bit_cast(s16x8, *(const u16x8*)(Vb + off));
                    o[nt] = __builtin_amdgcn_mfma_f32_16x16x32_bf16(pf, vf, o[nt], 0, 0, 0);
                }
            }
            __builtin_amdgcn_s_setprio(0);
        }

        if (hn) {
            *(u16x8*)((char*)Ksw[cur ^ 1] + soff) = kn;
            *(u16x8*)((char*)Vsw[cur ^ 1] + soff) = vn;
        }
        __syncthreads();
        cur ^= 1;
    }

    #pragma unroll
    for (int rr = 0; rr < 4; ++rr) {
        const float lq = __shfl(l, g * 4 + rr);
        const float inv = 1.0f / lq;
        const int q_g = qrow0 + g * 4 + rr;
        #pragma unroll
        for (int nt = 0; nt < 4; ++nt) {
            const int d = nt * 16 + l16;
            Ctx[((size_t)b * 2048 + q_g) * 1024 + h * 64 + d] = f2bf(o[nt][rr] * inv);
        }
    }
}

// =====================================================================
extern "C" void kernel_launch(void* const* d_in, const int* in_sizes, int n_in,
                              void* d_out, int out_size, void* d_ws, size_t ws_size,
                              hipStream_t stream)
{
    const float* q  = (const float*)d_in[0];
    const float* k  = (const float*)d_in[1];
    const float* v  = (const float*)d_in[2];
    const float* Wq = (const float*)d_in[4];
    const float* Wk = (const float*)d_in[5];
    const float* Wv = (const float*)d_in[6];
    const float* Wo = (const float*)d_in[7];

    const size_t NE = (size_t)4 * 16 * 2048 * 64;
    const size_t WE = (size_t)1024 * 1024;
    unsigned short* Qh = (unsigned short*)d_ws;
    unsigned short* Kh = Qh + NE;
    unsigned short* Vt = Kh + NE;
    float* outp = (float*)d_out;
    dim3 blk(256);

    if (ws_size >= 6 * NE * 2 + 4 * WE * 2) {
        unsigned short* qb  = Vt + NE;
        unsigned short* kb  = qb + NE;
        unsigned short* vb  = kb + NE;
        unsigned short* wb  = vb + NE;
        unsigned short* Ctx = qb;
        conv_kernel<<<dim3(14336), blk, 0, stream>>>(q, k, v, Wq, Wk, Wv, Wo,
                                                     qb, kb, vb, wb);
        gemmR<0><<<dim3(1536), blk, 0, stream>>>(
            qb, kb, vb, wb, Qh, Kh, Vt, nullptr);
        attn_kernel<<<dim3(1024), dim3(512), 0, stream>>>(Qh, Kh, Vt, Ctx);
        gemmR<1><<<dim3(512), blk, 0, stream>>>(
            Ctx, nullptr, nullptr, wb + 3 * WE, nullptr, nullptr, nullptr, outp);
    } else {
        unsigned short* Ctx = Vt + NE;
        gemm_k<1, 1, 0><<<dim3(1536), blk, 0, stream>>>(
            q, k, v, Wq, Wk, Wv, Qh, Kh, Vt, nullptr);
        attn_kernel<<<dim3(1024), dim3(512), 0, stream>>>(Qh, Kh, Vt, Ctx);
        gemm_k<0, 1, 1><<<dim3(512), blk, 0, stream>>>(
            Ctx, nullptr, nullptr, Wo, nullptr, nullptr,
            nullptr, nullptr, nullptr, outp);
    }
}

// Round 10
// 178.933 us; speedup vs baseline: 1.8246x; 1.8246x over previous
//
#include <hip/hip_runtime.h>

// ---------- types ----------
typedef __attribute__((ext_vector_type(4))) float  f32x4;
typedef __attribute__((ext_vector_type(8))) short  s16x8;   // 8 bf16 (4 VGPRs)
typedef __attribute__((ext_vector_type(8))) unsigned short u16x8;
typedef __attribute__((ext_vector_type(4))) unsigned short u16x4;
typedef __attribute__((ext_vector_type(4))) unsigned int   u32x4;

static __device__ __forceinline__ unsigned short f2bf(float f) {
    unsigned int u = __builtin_bit_cast(unsigned int, f);
    u += 0x7fffu + ((u >> 16) & 1u);      // round-to-nearest-even
    return (unsigned short)(u >> 16);
}

static __device__ __forceinline__ unsigned int cvt_pk_bf16(float lo, float hi) {
    unsigned int r;
    asm("v_cvt_pk_bf16_f32 %0, %1, %2" : "=v"(r) : "v"(lo), "v"(hi));
    return r;
}

static __device__ __forceinline__ void gload16(const void* g, void* l) {
    __builtin_amdgcn_global_load_lds(
        (const __attribute__((address_space(1))) void*)g,
        (__attribute__((address_space(3))) void*)l, 16, 0, 0);
}

// =====================================================================
// bf16 NT GEMM with IN-KERNEL fp32->bf16 staging (conv pass eliminated).
// 256x128 tile, BK=64, 8 waves (4M x 2N, 64x64 each), double-buffered
// swizzled LDS (96 KB), T14 stage-ahead:
//   iter t: {issue global loads for t+1 -> regs (or gload_lds for bf16 A)}
//           {ds_read cur + 32 MFMA}
//           {convert + swizzled ds_write t+1 -> buf^1}
//           {__syncthreads}
// EPI 0: A = q/k/v fp32, B = Wq/Wk/Wv fp32. grid 768, XCD-swizzled.
//        seg0 -> Qh [B,H,L,64] * 0.125 ; seg1 -> Kh ; seg2 -> Vt [B,H,64,L]
// EPI 1: A = Ctx bf16 (gload_lds), B = Wo fp32. grid 256. Of fp32.
// =====================================================================
template<int EPI>
__global__ __launch_bounds__(512)
void gemmF(const float* __restrict__ A0f, const float* __restrict__ A1f,
           const float* __restrict__ A2f, const unsigned short* __restrict__ Ab16,
           const float* __restrict__ B0f, const float* __restrict__ B1f,
           const float* __restrict__ B2f,
           unsigned short* __restrict__ O0, unsigned short* __restrict__ O1,
           unsigned short* __restrict__ O2, float* __restrict__ Of)
{
    __shared__ unsigned short Asw[2][256 * 64];   // 64 KB
    __shared__ unsigned short Bsw[2][128 * 64];   // 32 KB

    const int tid  = threadIdx.x;
    const int lane = tid & 63;
    const int wave = tid >> 6;
    const int wr   = wave >> 1, wc = wave & 1;    // 4M x 2N waves, 64x64 each
    const int g    = lane >> 4, l16 = lane & 15;

    const int nblk = (EPI == 0) ? 768 : 256;
    const int cpx  = nblk >> 3;
    const int wg   = (blockIdx.x & 7) * cpx + (blockIdx.x >> 3);  // bijective XCD swizzle
    const int bx   = wg & 7;
    const int byt  = wg >> 3;
    const int seg  = (EPI == 0) ? (byt >> 5) : 0;
    const int byl  = (EPI == 0) ? (byt & 31) : byt;

    const float* Arowf = nullptr;
    const unsigned short* Arowb = nullptr;
    if (EPI == 0) {
        const float* Af = seg == 0 ? A0f : seg == 1 ? A1f : A2f;
        Arowf = Af + (size_t)(byl * 256) * 1024;
    } else {
        Arowb = Ab16 + (size_t)(byl * 256) * 1024;
    }
    const float* Browf = (seg == 0 ? B0f : seg == 1 ? B1f : B2f)
                       + (size_t)(bx * 128) * 1024;

    f32x4 acc[4][4] = {};

    // staging registers for tile t+1 (fp32 path)
    f32x4 alo[4], ahi[4];   // A: 4 chunks x 8 floats (EPI 0 only)
    f32x4 blo[2], bhi[2];   // B: 2 chunks x 8 floats

    // chunk coords: chunk j covers row r=(j*512+tid)>>3, 16B-col c=tid&7
    auto loadAf = [&](int kt2) {
        #pragma unroll
        for (int j = 0; j < 4; ++j) {
            const float* p = Arowf + (size_t)((j * 512 + tid) >> 3) * 1024
                           + kt2 * 64 + (tid & 7) * 8;
            alo[j] = *(const f32x4*)p;
            ahi[j] = *(const f32x4*)(p + 4);
        }
    };
    auto loadBf = [&](int kt2) {
        #pragma unroll
        for (int j = 0; j < 2; ++j) {
            const float* p = Browf + (size_t)((j * 512 + tid) >> 3) * 1024
                           + kt2 * 64 + (tid & 7) * 8;
            blo[j] = *(const f32x4*)p;
            bhi[j] = *(const f32x4*)(p + 4);
        }
    };
    auto writeA = [&](int buf) {
        #pragma unroll
        for (int j = 0; j < 4; ++j) {
            const int r = (j * 512 + tid) >> 3, c = tid & 7;
            u32x4 w;
            w[0] = cvt_pk_bf16(alo[j][0], alo[j][1]);
            w[1] = cvt_pk_bf16(alo[j][2], alo[j][3]);
            w[2] = cvt_pk_bf16(ahi[j][0], ahi[j][1]);
            w[3] = cvt_pk_bf16(ahi[j][2], ahi[j][3]);
            *(u32x4*)((char*)Asw[buf] + ((r * 128 + c * 16) ^ ((r & 7) << 4))) = w;
        }
    };
    auto writeB = [&](int buf) {
        #pragma unroll
        for (int j = 0; j < 2; ++j) {
            const int r = (j * 512 + tid) >> 3, c = tid & 7;
            u32x4 w;
            w[0] = cvt_pk_bf16(blo[j][0], blo[j][1]);
            w[1] = cvt_pk_bf16(blo[j][2], blo[j][3]);
            w[2] = cvt_pk_bf16(bhi[j][0], bhi[j][1]);
            w[3] = cvt_pk_bf16(bhi[j][2], bhi[j][3]);
            *(u32x4*)((char*)Bsw[buf] + ((r * 128 + c * 16) ^ ((r & 7) << 4))) = w;
        }
    };
    // bf16 A staging (EPI 1): direct-to-LDS, linear dest + inv-swizzled source
    auto gloadA = [&](int buf, int kt2) {
        #pragma unroll
        for (int j = 0; j < 4; ++j) {
            const int r  = (j * 512 + tid) >> 3;
            const int cl = (tid & 7) ^ (r & 7);
            gload16(Arowb + (size_t)r * 1024 + kt2 * 64 + cl * 8,
                    (char*)Asw[buf] + j * 8192 + wave * 1024);
        }
    };
    auto lda = [&](const char* Ab, int mi, int ks) -> s16x8 {
        const int row = wr * 64 + mi * 16 + l16;
        const int off = (row * 128 + g * 16 + ks * 64) ^ ((row & 7) << 4);
        return __builtin_bit_cast(s16x8, *(const u16x8*)(Ab + off));
    };
    auto ldb = [&](const char* Bb, int ni, int ks) -> s16x8 {
        const int row = wc * 64 + ni * 16 + l16;
        const int off = (row * 128 + g * 16 + ks * 64) ^ ((row & 7) << 4);
        return __builtin_bit_cast(s16x8, *(const u16x8*)(Bb + off));
    };

    // ---- prologue: stage tile 0 into buf 0 ----
    if (EPI == 0) { loadAf(0); } else { gloadA(0, 0); }
    loadBf(0);
    if (EPI == 0) writeA(0);
    writeB(0);
    __syncthreads();

    int cur = 0;
    for (int t = 0; t < 16; ++t) {
        const bool hn = (t + 1 < 16);
        // issue next-tile global loads EARLY (latency hides under compute)
        if (hn) {
            if (EPI == 0) loadAf(t + 1); else gloadA(cur ^ 1, t + 1);
            loadBf(t + 1);
        }

        const char* Ab = (const char*)Asw[cur];
        const char* Bb = (const char*)Bsw[cur];
        #pragma unroll
        for (int ks = 0; ks < 2; ++ks) {
            s16x8 af[4], bf[4];
            #pragma unroll
            for (int mi = 0; mi < 4; ++mi) af[mi] = lda(Ab, mi, ks);
            #pragma unroll
            for (int ni = 0; ni < 4; ++ni) bf[ni] = ldb(Bb, ni, ks);
            __builtin_amdgcn_s_setprio(1);
            #pragma unroll
            for (int mi = 0; mi < 4; ++mi)
                #pragma unroll
                for (int ni = 0; ni < 4; ++ni)
                    acc[mi][ni] = __builtin_amdgcn_mfma_f32_16x16x32_bf16(
                        af[mi], bf[ni], acc[mi][ni], 0, 0, 0);
            __builtin_amdgcn_s_setprio(0);
        }

        // convert + write next tile into the other buffer
        if (hn) {
            if (EPI == 0) writeA(cur ^ 1);
            writeB(cur ^ 1);
        }
        __syncthreads();   // drains lgkm + vmcnt (gload_lds) before next reads
        cur ^= 1;
    }

    // ---- epilogue ----
    #pragma unroll
    for (int mi = 0; mi < 4; ++mi) {
        #pragma unroll
        for (int ni = 0; ni < 4; ++ni) {
            const int gr0 = byl * 256 + wr * 64 + mi * 16 + g * 4;      // M base
            const int gc  = bx * 128 + wc * 64 + ni * 16 + l16;         // N
            if (EPI == 0 && seg == 2) {
                // Vt [B,H,64,L]: pack 4 consecutive ll into one 8B store
                const int b = gr0 >> 11, ll = gr0 & 2047;
                const int h = gc >> 6,  dh = gc & 63;
                u16x4 pk;
                #pragma unroll
                for (int rr = 0; rr < 4; ++rr) pk[rr] = f2bf(acc[mi][ni][rr]);
                *(u16x4*)(O2 + (size_t)((b * 16 + h) * 64 + dh) * 2048 + ll) = pk;
            } else {
                #pragma unroll
                for (int rr = 0; rr < 4; ++rr) {
                    const int gr = gr0 + rr;
                    float v = acc[mi][ni][rr];
                    if (EPI == 0) {
                        const int b = gr >> 11, ll = gr & 2047;
                        const int h = gc >> 6,  dh = gc & 63;
                        if (seg == 0) {
                            v *= 0.125f;
                            O0[(size_t)((b * 16 + h) * 2048 + ll) * 64 + dh] = f2bf(v);
                        } else {
                            O1[(size_t)((b * 16 + h) * 2048 + ll) * 64 + dh] = f2bf(v);
                        }
                    } else {
                        Of[(size_t)gr * 1024 + gc] = v;
                    }
                }
            }
        }
    }
}

// =====================================================================
// Flash-style causal attention, double-buffered KV.
// Swapped QK^T (S^T = mfma(K,Q)) -> per-lane row softmax (q = l16),
// defer-max (THR=8), cvt_pk P->bf16, b64 P writes.  (unchanged)
// =====================================================================
__global__ __launch_bounds__(512)
void attn_kernel(const unsigned short* __restrict__ Qh,
                 const unsigned short* __restrict__ Kh,
                 const unsigned short* __restrict__ Vt,
                 unsigned short* __restrict__ Ctx)
{
    __shared__ unsigned short Ksw[2][64 * 64];
    __shared__ unsigned short Vsw[2][64 * 64];
    __shared__ unsigned short Psw[8][16 * 64];

    const int tid  = threadIdx.x;
    const int lane = tid & 63;
    const int wave = tid >> 6;
    const int g    = lane >> 4, l16 = lane & 15;
    const int qb   = 15 - (int)(blockIdx.x >> 6);
    const int bh   = blockIdx.x & 63;
    const int b    = bh >> 4, h = bh & 15;
    const int qrow0 = qb * 128 + wave * 16;
    const int ntile = 2 * qb + 2;

    const int sr = tid >> 3, sc = tid & 7;
    const int soff = (sr * 128 + sc * 16) ^ ((sr & 7) << 4);
    const unsigned short* kbase = Kh + ((size_t)bh * 2048 + sr) * 64 + sc * 8;
    const unsigned short* vbase = Vt + ((size_t)bh * 64 + sr) * 2048 + sc * 8;

    s16x8 qf[2];
    {
        const unsigned short* qp = Qh + ((size_t)bh * 2048 + qrow0 + l16) * 64 + g * 8;
        qf[0] = __builtin_bit_cast(s16x8, *(const u16x8*)qp);
        qf[1] = __builtin_bit_cast(s16x8, *(const u16x8*)(qp + 32));
    }

    f32x4 o[4] = {};
    float m = -3.0e38f, l = 0.f;   // per-lane row state: q = l16

    *(u16x8*)((char*)Ksw[0] + soff) = *(const u16x8*)kbase;
    *(u16x8*)((char*)Vsw[0] + soff) = *(const u16x8*)vbase;
    __syncthreads();

    int cur = 0;
    for (int t = 0; t < ntile; ++t) {
        const int kv0 = t * 64;

        u16x8 kn, vn;
        const bool hn = (t + 1 < ntile);
        if (hn) {
            kn = *(const u16x8*)(kbase + (size_t)(kv0 + 64) * 64);
            vn = *(const u16x8*)(vbase + (kv0 + 64));
        }

        if (kv0 <= qrow0 + 15) {
            const char* Kb = (const char*)Ksw[cur];
            const char* Vb = (const char*)Vsw[cur];

            f32x4 st[4] = {};
            __builtin_amdgcn_s_setprio(1);
            #pragma unroll
            for (int nt = 0; nt < 4; ++nt) {
                #pragma unroll
                for (int ks = 0; ks < 2; ++ks) {
                    const int row = nt * 16 + l16;
                    const int off = (row * 128 + g * 16 + ks * 64) ^ ((row & 7) << 4);
                    s16x8 kf = __builtin_bit_cast(s16x8, *(const u16x8*)(Kb + off));
                    st[nt] = __builtin_amdgcn_mfma_f32_16x16x32_bf16(kf, qf[ks], st[nt], 0, 0, 0);
                }
            }
            __builtin_amdgcn_s_setprio(0);

            if (kv0 + 63 > qrow0) {
                const int q_g = qrow0 + l16;
                #pragma unroll
                for (int nt = 0; nt < 4; ++nt)
                    #pragma unroll
                    for (int rr = 0; rr < 4; ++rr) {
                        const int kv_g = kv0 + nt * 16 + g * 4 + rr;
                        if (kv_g > q_g) st[nt][rr] = -3.0e38f;
                    }
            }

            float pmax = fmaxf(
                fmaxf(fmaxf(fmaxf(st[0][0], st[0][1]), fmaxf(st[0][2], st[0][3])),
                      fmaxf(fmaxf(st[1][0], st[1][1]), fmaxf(st[1][2], st[1][3]))),
                fmaxf(fmaxf(fmaxf(st[2][0], st[2][1]), fmaxf(st[2][2], st[2][3])),
                      fmaxf(fmaxf(st[3][0], st[3][1]), fmaxf(st[3][2], st[3][3]))));
            pmax = fmaxf(pmax, __shfl_xor(pmax, 16));
            pmax = fmaxf(pmax, __shfl_xor(pmax, 32));

            if (__all(pmax <= m + 8.0f)) {
                float r0 = 0.f;
                #pragma unroll
                for (int nt = 0; nt < 4; ++nt)
                    #pragma unroll
                    for (int rr = 0; rr < 4; ++rr) {
                        const float p = __expf(st[nt][rr] - m);
                        st[nt][rr] = p;
                        r0 += p;
                    }
                r0 += __shfl_xor(r0, 16);
                r0 += __shfl_xor(r0, 32);
                l += r0;
            } else {
                const float mn = fmaxf(m, pmax);
                const float scf = __expf(m - mn);
                m = mn;
                float r0 = 0.f;
                #pragma unroll
                for (int nt = 0; nt < 4; ++nt)
                    #pragma unroll
                    for (int rr = 0; rr < 4; ++rr) {
                        const float p = __expf(st[nt][rr] - mn);
                        st[nt][rr] = p;
                        r0 += p;
                    }
                r0 += __shfl_xor(r0, 16);
                r0 += __shfl_xor(r0, 32);
                l = l * scf + r0;
                float sc4[4];
                #pragma unroll
                for (int rr = 0; rr < 4; ++rr) sc4[rr] = __shfl(scf, g * 4 + rr);
                #pragma unroll
                for (int nt = 0; nt < 4; ++nt)
                    #pragma unroll
                    for (int rr = 0; rr < 4; ++rr)
                        o[nt][rr] *= sc4[rr];
            }

            unsigned short* Pw = Psw[wave];
            #pragma unroll
            for (int nt = 0; nt < 4; ++nt) {
                const unsigned int w0 = cvt_pk_bf16(st[nt][0], st[nt][1]);
                const unsigned int w1 = cvt_pk_bf16(st[nt][2], st[nt][3]);
                const int off = (l16 * 128 + nt * 32 + g * 8) ^ ((l16 & 7) << 4);
                const unsigned long long dw = ((unsigned long long)w1 << 32) | w0;
                *(unsigned long long*)((char*)Pw + off) = dw;
            }

            __builtin_amdgcn_s_setprio(1);
            #pragma unroll
            for (int ks = 0; ks < 2; ++ks) {
                const int offp = (l16 * 128 + g * 16 + ks * 64) ^ ((l16 & 7) << 4);
                s16x8 pf = __builtin_bit_cast(s16x8, *(const u16x8*)((const char*)Pw + offp));
                #pragma unroll
                for (int nt = 0; nt < 4; ++nt) {
                    const int row = nt * 16 + l16;
                    const int off = (row * 128 + g * 16 + ks * 64) ^ ((row & 7) << 4);
                    s16x8 vf = __builtin_bit_cast(s16x8, *(const u16x8*)(Vb + off));
                    o[nt] = __builtin_amdgcn_mfma_f32_16x16x32_bf16(pf, vf, o[nt], 0, 0, 0);
                }
            }
            __builtin_amdgcn_s_setprio(0);
        }

        if (hn) {
            *(u16x8*)((char*)Ksw[cur ^ 1] + soff) = kn;
            *(u16x8*)((char*)Vsw[cur ^ 1] + soff) = vn;
        }
        __syncthreads();
        cur ^= 1;
    }

    #pragma unroll
    for (int rr = 0; rr < 4; ++rr) {
        const float lq = __shfl(l, g * 4 + rr);
        const float inv = 1.0f / lq;
        const int q_g = qrow0 + g * 4 + rr;
        #pragma unroll
        for (int nt = 0; nt < 4; ++nt) {
            const int d = nt * 16 + l16;
            Ctx[((size_t)b * 2048 + q_g) * 1024 + h * 64 + d] = f2bf(o[nt][rr] * inv);
        }
    }
}

// =====================================================================
extern "C" void kernel_launch(void* const* d_in, const int* in_sizes, int n_in,
                              void* d_out, int out_size, void* d_ws, size_t ws_size,
                              hipStream_t stream)
{
    const float* q  = (const float*)d_in[0];
    const float* k  = (const float*)d_in[1];
    const float* v  = (const float*)d_in[2];
    const float* Wq = (const float*)d_in[4];
    const float* Wk = (const float*)d_in[5];
    const float* Wv = (const float*)d_in[6];
    const float* Wo = (const float*)d_in[7];

    const size_t NE = (size_t)4 * 16 * 2048 * 64;     // 8,388,608 elems / tensor
    unsigned short* Qh  = (unsigned short*)d_ws;
    unsigned short* Kh  = Qh + NE;
    unsigned short* Vt  = Kh + NE;
    unsigned short* Ctx = Vt + NE;                    // 64 MB total (ws >= 67.1 MB proven)
    float* outp = (float*)d_out;

    // fused QKV projections, fp32 inputs converted in-kernel
    gemmF<0><<<dim3(768), dim3(512), 0, stream>>>(
        q, k, v, nullptr, Wq, Wk, Wv, Qh, Kh, Vt, nullptr);
    attn_kernel<<<dim3(1024), dim3(512), 0, stream>>>(Qh, Kh, Vt, Ctx);
    // output projection: Ctx bf16 x Wo fp32 -> fp32 out
    gemmF<1><<<dim3(256), dim3(512), 0, stream>>>(
        nullptr, nullptr, nullptr, Ctx, Wo, nullptr, nullptr,
        nullptr, nullptr, nullptr, outp);
}